// Round 2
// baseline (19848.064 us; speedup 1.0000x reference)
//
#include <hip/hip_runtime.h>
#include <hip/hip_bf16.h>
#include <hip/hip_cooperative_groups.h>

namespace cg = cooperative_groups;

typedef __bf16 bf16_t;
typedef __bf16 bf16x8_t __attribute__((ext_vector_type(8)));
typedef __bf16 bf16x4_t __attribute__((ext_vector_type(4)));
typedef float  f32x4_t  __attribute__((ext_vector_type(4)));
typedef unsigned int u32x4_t __attribute__((ext_vector_type(4)));
typedef unsigned int u32x2_t __attribute__((ext_vector_type(2)));

#define NSTEPS 512
#define NB     64
#define NIN    512
#define NH     1024
#define KTOT   1536   /* NIN + NH */

/* LDS layout (bytes) */
#define WBUF_BYTES (32 * KTOT * 2)          /* 98304: 32 gate rows x 1536 K, bf16, swizzled */
#define ABUF_OFF   WBUF_BYTES
#define ABUF_BYTES (32 * 512 * 2)           /* 32768: 32 batches x 512 K stage, bf16, swizzled */
#define GBUF_OFF   (ABUF_OFF + ABUF_BYTES)  /* 131072 */
#define GBUF_BYTES (32 * 33 * 4)            /* 4224: gate exchange, +1 pad */
#define SMEM_BYTES (GBUF_OFF + GBUF_BYTES)  /* 135296 */

__device__ __forceinline__ float sigmoid_f(float x) {
    return 1.0f / (1.0f + __expf(-x));
}
__device__ __forceinline__ float tanh_f(float x) {
    /* 1 - 2/(e^{2x}+1); saturates correctly at +-inf */
    return 1.0f - 2.0f / (__expf(2.0f * x) + 1.0f);
}

__global__ void __launch_bounds__(256, 1)
lstm_fused(const float* __restrict__ xs, const float* __restrict__ h0,
           const float* __restrict__ c0, const float* __restrict__ Wih,
           const float* __restrict__ Whh, const float* __restrict__ bih,
           const float* __restrict__ bhh, float* __restrict__ out,
           bf16_t* __restrict__ hb0, bf16_t* __restrict__ hb1)
{
    extern __shared__ char smem[];

    const int tid = threadIdx.x;
    const int bid = blockIdx.x;
    const int bt  = bid & 1;       /* batch tile: 32 batches */
    const int ht  = bid >> 1;      /* hidden tile: 8 units (0..127) */

    /* ---- stage weight slice into LDS: rows = 4 gates x 8 units, K = [x | h] ---- */
    {
        const int lr = tid >> 3;                 /* local row 0..31 */
        const int t8 = tid & 7;
        const int g  = lr >> 3;
        const int u  = lr & 7;
        const int R  = g * NH + ht * 8 + u;      /* global gate row in [0,4096) */
        const unsigned rowbase = (unsigned)lr * (KTOT * 2);
        const unsigned swz = (unsigned)((lr & 7) << 4);
        #pragma unroll 4
        for (int j = 0; j < 48; ++j) {
            const int kc = t8 + j * 8;           /* float4 chunk 0..383 */
            const int k  = kc * 4;
            f32x4_t w;
            if (k < NIN) w = *reinterpret_cast<const f32x4_t*>(Wih + (size_t)R * NIN + k);
            else         w = *reinterpret_cast<const f32x4_t*>(Whh + (size_t)R * NH + (k - NIN));
            union { bf16x4_t b; u32x2_t v; } cv;
            cv.b[0] = (bf16_t)w[0]; cv.b[1] = (bf16_t)w[1];
            cv.b[2] = (bf16_t)w[2]; cv.b[3] = (bf16_t)w[3];
            const unsigned byte = (rowbase + (unsigned)(k * 2)) ^ swz;
            *reinterpret_cast<u32x2_t*>(smem + byte) = cv.v;
        }
    }

    /* ---- init h ping buffer from h0 (grid exactly covers NB*NH = 65536) ---- */
    {
        const int gid = bid * 256 + tid;
        hb0[gid] = (bf16_t)h0[gid];
    }

    /* ---- per-thread owned cell state: (batch em, unit eu) ---- */
    const int em = tid >> 3;            /* 0..31 */
    const int eu = tid & 7;             /* 0..7  */
    const int gb = bt * 32 + em;        /* global batch */
    const int gj = ht * 8 + eu;         /* global hidden idx */
    float c_reg = c0[(size_t)gb * NH + gj];

    /* ---- MFMA fragment constants (2x2 wave tiling of 32x32 output) ---- */
    const int lane = tid & 63;
    const int wid  = tid >> 6;
    const int mi   = wid >> 1;                       /* M tile (batches) */
    const int ni   = wid & 1;                        /* N tile (gate rows) */
    const int nloc = ni * 16 + (lane & 15);          /* B-col = local gate row */
    const int arow = mi * 16 + (lane & 15);          /* A-row = local batch */
    const int kg   = (lane >> 4) * 8;                /* k sub-offset per 16-lane group */
    const unsigned aswz  = (unsigned)((arow & 7) << 4);
    const unsigned bswz  = (unsigned)((nloc & 7) << 4);
    const unsigned abase = (unsigned)(arow * 1024 + kg * 2);

    float bias_r;
    {
        const int g = nloc >> 3, u = nloc & 7;
        const int N = g * NH + ht * 8 + u;
        bias_r = bih[N] + bhh[N];
    }
    float* gbuf = reinterpret_cast<float*>(smem + GBUF_OFF);

    cg::grid_group grid = cg::this_grid();
    grid.sync();   /* hb0 + weights ready */

    for (int t = 0; t < NSTEPS; ++t) {
        const bf16_t* __restrict__ hcur = (t & 1) ? hb1 : hb0;
        bf16_t* __restrict__ hnxt       = (t & 1) ? hb0 : hb1;

        f32x4_t acc = { bias_r, bias_r, bias_r, bias_r };

        #pragma unroll
        for (int p = 0; p < 3; ++p) {
            __syncthreads();   /* previous phase done reading abuf */
            if (p == 0) {
                /* stage x_t tile: 32 batches x 512, fp32 -> bf16, swizzled */
                const float* xbase = xs + ((size_t)t * NB + bt * 32) * NIN;
                #pragma unroll
                for (int i = 0; i < 16; ++i) {
                    const int c  = tid + i * 256;    /* 0..4095 float4 chunks */
                    const int r  = c >> 7;
                    const int kc = c & 127;
                    f32x4_t v = *reinterpret_cast<const f32x4_t*>(xbase + (size_t)r * NIN + kc * 4);
                    union { bf16x4_t b; u32x2_t w; } cv;
                    cv.b[0] = (bf16_t)v[0]; cv.b[1] = (bf16_t)v[1];
                    cv.b[2] = (bf16_t)v[2]; cv.b[3] = (bf16_t)v[3];
                    const unsigned byte = ((unsigned)(r * 1024 + kc * 8)) ^ ((unsigned)((r & 7) << 4));
                    *reinterpret_cast<u32x2_t*>(smem + ABUF_OFF + byte) = cv.w;
                }
            } else {
                /* stage h half-tile: 32 batches x 512, bf16 copy, swizzled */
                const int koff = (p - 1) * 512;
                const bf16_t* hbase = hcur + (size_t)(bt * 32) * NH + koff;
                #pragma unroll
                for (int i = 0; i < 8; ++i) {
                    const int c  = tid + i * 256;    /* 0..2047 16B chunks */
                    const int r  = c >> 6;
                    const int kc = c & 63;
                    u32x4_t v = *reinterpret_cast<const u32x4_t*>(hbase + (size_t)r * NH + kc * 8);
                    const unsigned byte = ((unsigned)(r * 1024 + kc * 16)) ^ ((unsigned)((r & 7) << 4));
                    *reinterpret_cast<u32x4_t*>(smem + ABUF_OFF + byte) = v;
                }
            }
            __syncthreads();   /* stage visible */

            const unsigned bbase = (unsigned)(nloc * (KTOT * 2) + (p * 512 + kg) * 2);
            #pragma unroll
            for (int kk = 0; kk < 16; ++kk) {
                bf16x8_t af  = *reinterpret_cast<const bf16x8_t*>(smem + ABUF_OFF + ((abase + kk * 64) ^ aswz));
                bf16x8_t bfr = *reinterpret_cast<const bf16x8_t*>(smem + ((bbase + kk * 64) ^ bswz));
                acc = __builtin_amdgcn_mfma_f32_16x16x32_bf16(af, bfr, acc, 0, 0, 0);
            }
        }

        /* ---- exchange gates via LDS: D layout col=lane&15, row=(lane>>4)*4+reg ---- */
        {
            const int mbase = mi * 16 + ((lane >> 4) << 2);
            #pragma unroll
            for (int r = 0; r < 4; ++r)
                gbuf[(mbase + r) * 33 + nloc] = acc[r];
        }
        __syncthreads();

        /* ---- elementwise gate math; each thread owns (em, eu) ---- */
        {
            const float gi = gbuf[em * 33 +      eu];
            const float gf = gbuf[em * 33 +  8 + eu];
            const float gc = gbuf[em * 33 + 16 + eu];
            const float go = gbuf[em * 33 + 24 + eu];
            const float i_ = sigmoid_f(gi);
            const float f_ = sigmoid_f(gf);
            const float g_ = tanh_f(gc);
            const float o_ = sigmoid_f(go);
            c_reg = f_ * c_reg + i_ * g_;
            const float h_ = o_ * tanh_f(c_reg);
            out[((size_t)t * NB + gb) * NH + gj] = h_;
            hnxt[(size_t)gb * NH + gj] = (bf16_t)h_;
        }

        grid.sync();   /* hnxt globally visible before next step's staging */
    }
}

extern "C" void kernel_launch(void* const* d_in, const int* in_sizes, int n_in,
                              void* d_out, int out_size, void* d_ws, size_t ws_size,
                              hipStream_t stream)
{
    const float* xs  = (const float*)d_in[0];
    const float* h0  = (const float*)d_in[1];
    const float* c0  = (const float*)d_in[2];
    const float* Wih = (const float*)d_in[3];
    const float* Whh = (const float*)d_in[4];
    const float* bih = (const float*)d_in[5];
    const float* bhh = (const float*)d_in[6];
    float* out = (float*)d_out;

    bf16_t* hb0 = (bf16_t*)d_ws;                     /* 128 KB */
    bf16_t* hb1 = hb0 + (size_t)NB * NH;             /* 128 KB */

    (void)hipFuncSetAttribute((const void*)lstm_fused,
                              hipFuncAttributeMaxDynamicSharedMemorySize,
                              SMEM_BYTES);

    void* args[] = { &xs, &h0, &c0, &Wih, &Whh, &bih, &bhh, &out, &hb0, &hb1 };
    (void)hipLaunchCooperativeKernel((void*)lstm_fused, dim3(256), dim3(256),
                                     args, (unsigned)SMEM_BYTES, stream);
}

// Round 5
// 16728.522 us; speedup vs baseline: 1.1865x; 1.1865x over previous
//
#include <hip/hip_runtime.h>
#include <hip/hip_bf16.h>

typedef __bf16 bf16_t;
typedef __bf16 bf16x8_t __attribute__((ext_vector_type(8)));
typedef __bf16 bf16x4_t __attribute__((ext_vector_type(4)));
typedef float  f32x4_t  __attribute__((ext_vector_type(4)));
typedef unsigned int u32x2_t __attribute__((ext_vector_type(2)));

#define NSTEPS 512
#define NB     64
#define NIN    512
#define NH     1024
#define KTOT   1536   /* NIN + NH */

/* LDS layout (bytes) */
#define WBUF_BYTES (32 * KTOT * 2)          /* 98304: 32 gate rows x 1536 K, bf16, swizzled */
#define ABUF_OFF   WBUF_BYTES
#define ABUF_BYTES (32 * 512 * 2)           /* 32768: 32 x 512 stage, bf16, swizzled */
#define GBUF_OFF   (ABUF_OFF + ABUF_BYTES)  /* 131072 */
#define GBUF_BYTES (32 * 33 * 4)            /* 4224: gate exchange, +1 pad */
#define SMEM_BYTES (GBUF_OFF + GBUF_BYTES)  /* 135296 */

__device__ __forceinline__ float sigmoid_f(float x) {
    return 1.0f / (1.0f + __expf(-x));
}
__device__ __forceinline__ float tanh_f(float x) {
    return 1.0f - 2.0f / (__expf(2.0f * x) + 1.0f);
}

/* convert 4 fp32 -> bf16x4 and store swizzled into the 32x512 stage tile */
__device__ __forceinline__ void stage4(char* abuf, int c, f32x4_t v) {
    const int r  = c >> 7;       /* row 0..31 */
    const int kc = c & 127;      /* 4-col chunk */
    union { bf16x4_t b; u32x2_t w; } cv;
    cv.b[0] = (bf16_t)v[0]; cv.b[1] = (bf16_t)v[1];
    cv.b[2] = (bf16_t)v[2]; cv.b[3] = (bf16_t)v[3];
    const unsigned byte = ((unsigned)(r * 1024 + kc * 8)) ^ ((unsigned)((r & 7) << 4));
    *reinterpret_cast<u32x2_t*>(abuf + byte) = cv.w;
}

__global__ void flag_init(int* flags) {
    flags[threadIdx.x] = 0;   /* 256 ints = 1 KB at d_ws+0 */
}

__global__ void __launch_bounds__(256, 1)
lstm_fused(const float* __restrict__ xs, const float* __restrict__ h0,
           const float* __restrict__ c0, const float* __restrict__ Wih,
           const float* __restrict__ Whh, const float* __restrict__ bih,
           const float* __restrict__ bhh, float* __restrict__ out,
           int* __restrict__ flags)
{
    extern __shared__ char smem[];
    char* abuf = smem + ABUF_OFF;

    const int tid = threadIdx.x;
    const int bid = blockIdx.x;
    const int bt  = bid & 1;       /* batch group: 32 batches */
    const int ht  = bid >> 1;      /* hidden tile: 8 units (0..127) */
    int* gflags = flags + bt * 128;
    const int myslot = bid >> 1;

    /* ---- stage weight slice into LDS: rows = 4 gates x 8 units, K = [x | h] ---- */
    {
        const int lr = tid >> 3;                 /* local row 0..31 */
        const int t8 = tid & 7;
        const int g  = lr >> 3;
        const int u  = lr & 7;
        const int R  = g * NH + ht * 8 + u;      /* global gate row in [0,4096) */
        const unsigned rowbase = (unsigned)lr * (KTOT * 2);
        const unsigned swz = (unsigned)((lr & 7) << 4);
        #pragma unroll 4
        for (int j = 0; j < 48; ++j) {
            const int kc = t8 + j * 8;           /* float4 chunk 0..383 */
            const int k  = kc * 4;
            f32x4_t w;
            if (k < NIN) w = *reinterpret_cast<const f32x4_t*>(Wih + (size_t)R * NIN + k);
            else         w = *reinterpret_cast<const f32x4_t*>(Whh + (size_t)R * NH + (k - NIN));
            union { bf16x4_t b; u32x2_t v; } cv;
            cv.b[0] = (bf16_t)w[0]; cv.b[1] = (bf16_t)w[1];
            cv.b[2] = (bf16_t)w[2]; cv.b[3] = (bf16_t)w[3];
            const unsigned byte = (rowbase + (unsigned)(k * 2)) ^ swz;
            *reinterpret_cast<u32x2_t*>(smem + byte) = cv.v;
        }
    }

    /* ---- per-thread owned cell state: (batch em, unit eu) ---- */
    const int em = tid >> 3;            /* 0..31 */
    const int eu = tid & 7;             /* 0..7  */
    const int gb = bt * 32 + em;        /* global batch */
    const int gj = ht * 8 + eu;         /* global hidden idx */
    float c_reg = c0[(size_t)gb * NH + gj];

    /* ---- MFMA fragment constants (2x2 wave tiling of 32x32 output) ---- */
    const int lane = tid & 63;
    const int wid  = tid >> 6;
    const int mi   = wid >> 1;                       /* M tile (batches) */
    const int ni   = wid & 1;                        /* N tile (gate rows) */
    const int nloc = ni * 16 + (lane & 15);          /* B-col = local gate row */
    const int arow = mi * 16 + (lane & 15);          /* A-row = local batch */
    const int kg   = (lane >> 4) * 8;                /* k sub-offset per 16-lane group */
    const unsigned aswz  = (unsigned)((arow & 7) << 4);
    const unsigned bswz  = (unsigned)((nloc & 7) << 4);
    const unsigned abase = (unsigned)(arow * 1024 + kg * 2);

    float bias_r;
    {
        const int g = nloc >> 3, u = nloc & 7;
        const int N = g * NH + ht * 8 + u;
        bias_r = bih[N] + bhh[N];
    }
    float* gbuf = reinterpret_cast<float*>(smem + GBUF_OFF);

    /* ---- prefetch x_0 into registers ---- */
    f32x4_t xr[16];
    {
        const float* xbase = xs + (size_t)(bt * 32) * NIN;
        #pragma unroll
        for (int i = 0; i < 16; ++i) {
            const int c = tid + i * 256;
            xr[i] = *reinterpret_cast<const f32x4_t*>(xbase + (size_t)(c >> 7) * NIN + (c & 127) * 4);
        }
    }

    for (int t = 0; t < NSTEPS; ++t) {
        /* h source: out[t-1] (fp32) for t>0, else h0. Own group's rows only. */
        const float* hsrc = t ? (out + ((size_t)(t - 1) * NB + bt * 32) * NH)
                              : (h0 + (size_t)(bt * 32) * NH);

        /* issue all h loads up front — latency hidden by x staging + phase-0 MFMA */
        f32x4_t hA[16], hB[16];
        #pragma unroll
        for (int i = 0; i < 16; ++i) {
            const int c = tid + i * 256;
            hA[i] = *reinterpret_cast<const f32x4_t*>(hsrc + (size_t)(c >> 7) * NH + (c & 127) * 4);
        }
        #pragma unroll
        for (int i = 0; i < 16; ++i) {
            const int c = tid + i * 256;
            hB[i] = *reinterpret_cast<const f32x4_t*>(hsrc + (size_t)(c >> 7) * NH + 512 + (c & 127) * 4);
        }

        f32x4_t acc = { bias_r, bias_r, bias_r, bias_r };

        /* ===== phase 0: x_t ===== */
        __syncthreads();                        /* S1: abuf free (prev step done) */
        #pragma unroll
        for (int i = 0; i < 16; ++i) stage4(abuf, tid + i * 256, xr[i]);
        __syncthreads();                        /* S2 */
        {
            const unsigned bbase = (unsigned)(nloc * (KTOT * 2) + kg * 2);
            #pragma unroll
            for (int kk = 0; kk < 16; ++kk) {
                bf16x8_t af  = *reinterpret_cast<const bf16x8_t*>(abuf + ((abase + kk * 64) ^ aswz));
                bf16x8_t bfr = *reinterpret_cast<const bf16x8_t*>(smem + ((bbase + kk * 64) ^ bswz));
                acc = __builtin_amdgcn_mfma_f32_16x16x32_bf16(af, bfr, acc, 0, 0, 0);
            }
        }
        /* prefetch x_{t+1}: covered by phases 1-2 + gate math + barrier */
        if (t + 1 < NSTEPS) {
            const float* xbase = xs + ((size_t)(t + 1) * NB + bt * 32) * NIN;
            #pragma unroll
            for (int i = 0; i < 16; ++i) {
                const int c = tid + i * 256;
                xr[i] = *reinterpret_cast<const f32x4_t*>(xbase + (size_t)(c >> 7) * NIN + (c & 127) * 4);
            }
        }

        /* ===== phase 1: h cols [0,512) ===== */
        __syncthreads();                        /* S3: phase-0 mfma done */
        #pragma unroll
        for (int i = 0; i < 16; ++i) stage4(abuf, tid + i * 256, hA[i]);
        __syncthreads();                        /* S4 */
        {
            const unsigned bbase = (unsigned)(nloc * (KTOT * 2) + (512 + kg) * 2);
            #pragma unroll
            for (int kk = 0; kk < 16; ++kk) {
                bf16x8_t af  = *reinterpret_cast<const bf16x8_t*>(abuf + ((abase + kk * 64) ^ aswz));
                bf16x8_t bfr = *reinterpret_cast<const bf16x8_t*>(smem + ((bbase + kk * 64) ^ bswz));
                acc = __builtin_amdgcn_mfma_f32_16x16x32_bf16(af, bfr, acc, 0, 0, 0);
            }
        }

        /* ===== phase 2: h cols [512,1024) ===== */
        __syncthreads();                        /* S5 */
        #pragma unroll
        for (int i = 0; i < 16; ++i) stage4(abuf, tid + i * 256, hB[i]);
        __syncthreads();                        /* S6 */
        {
            const unsigned bbase = (unsigned)(nloc * (KTOT * 2) + (1024 + kg) * 2);
            #pragma unroll
            for (int kk = 0; kk < 16; ++kk) {
                bf16x8_t af  = *reinterpret_cast<const bf16x8_t*>(abuf + ((abase + kk * 64) ^ aswz));
                bf16x8_t bfr = *reinterpret_cast<const bf16x8_t*>(smem + ((bbase + kk * 64) ^ bswz));
                acc = __builtin_amdgcn_mfma_f32_16x16x32_bf16(af, bfr, acc, 0, 0, 0);
            }
        }

        /* ---- exchange gates via LDS: D layout col=lane&15, row=(lane>>4)*4+reg ---- */
        {
            const int mbase = mi * 16 + ((lane >> 4) << 2);
            #pragma unroll
            for (int r = 0; r < 4; ++r)
                gbuf[(mbase + r) * 33 + nloc] = acc[r];
        }
        __syncthreads();                        /* S7 */

        /* ---- elementwise gate math; each thread owns (em, eu) ---- */
        {
            const float gi = gbuf[em * 33 +      eu];
            const float gf = gbuf[em * 33 +  8 + eu];
            const float gc = gbuf[em * 33 + 16 + eu];
            const float go = gbuf[em * 33 + 24 + eu];
            const float i_ = sigmoid_f(gi);
            const float f_ = sigmoid_f(gf);
            const float g_ = tanh_f(gc);
            const float o_ = sigmoid_f(go);
            c_reg = f_ * c_reg + i_ * g_;
            const float h_ = o_ * tanh_f(c_reg);
            out[((size_t)t * NB + gb) * NH + gj] = h_;
        }

        /* ---- group barrier via monotonic per-block flags (tag = t+1) ---- */
        if (t + 1 < NSTEPS) {
            __syncthreads();                    /* S8: block's out-writes drained */
            if (tid == 0) {
                __threadfence();                /* writeback XCD L2: whole block's stores */
                __hip_atomic_store(&gflags[myslot], t + 1,
                                   __ATOMIC_RELEASE, __HIP_MEMORY_SCOPE_AGENT);
            }
            if (tid < 128) {
                int spins = 0;
                while (__hip_atomic_load(&gflags[tid], __ATOMIC_RELAXED,
                                         __HIP_MEMORY_SCOPE_AGENT) < t + 1) {
                    __builtin_amdgcn_s_sleep(2);
                    if (++spins > (1 << 20)) break;   /* bounded: fail loud, not hang */
                }
            }
            __syncthreads();                    /* S9: all 128 producers observed */
            __threadfence();                    /* acquire: invalidate stale h lines */
        }
    }
}

extern "C" void kernel_launch(void* const* d_in, const int* in_sizes, int n_in,
                              void* d_out, int out_size, void* d_ws, size_t ws_size,
                              hipStream_t stream)
{
    const float* xs  = (const float*)d_in[0];
    const float* h0  = (const float*)d_in[1];
    const float* c0  = (const float*)d_in[2];
    const float* Wih = (const float*)d_in[3];
    const float* Whh = (const float*)d_in[4];
    const float* bih = (const float*)d_in[5];
    const float* bhh = (const float*)d_in[6];
    float* out = (float*)d_out;

    int* flags = (int*)d_ws;   /* 1 KB at offset 0 — in-bounds for any ws_size */

    flag_init<<<1, 256, 0, stream>>>(flags);

    (void)hipFuncSetAttribute((const void*)lstm_fused,
                              hipFuncAttributeMaxDynamicSharedMemorySize,
                              SMEM_BYTES);

    void* args[] = { &xs, &h0, &c0, &Wih, &Whh, &bih, &bhh, &out, &flags };
    hipError_t e = hipLaunchCooperativeKernel((void*)lstm_fused, dim3(256), dim3(256),
                                              args, (unsigned)SMEM_BYTES, stream);
    if (e != hipSuccess) {
        (void)hipGetLastError();   /* clear sticky error, then plain launch:    */
        /* grid=256=#CUs and 132KB LDS force 1 block/CU -> co-resident anyway. */
        lstm_fused<<<dim3(256), dim3(256), SMEM_BYTES, stream>>>(
            xs, h0, c0, Wih, Whh, bih, bhh, out, flags);
    }
}

// Round 6
// 5347.388 us; speedup vs baseline: 3.7117x; 3.1284x over previous
//
#include <hip/hip_runtime.h>
#include <hip/hip_bf16.h>

typedef __bf16 bf16_t;
typedef __bf16 bf16x8_t __attribute__((ext_vector_type(8)));
typedef __bf16 bf16x4_t __attribute__((ext_vector_type(4)));
typedef float  f32x4_t  __attribute__((ext_vector_type(4)));
typedef unsigned int u32x2_t __attribute__((ext_vector_type(2)));
typedef unsigned long long u64;

#define NSTEPS 512
#define NB     64
#define NIN    512
#define NH     1024
#define KTOT   1536   /* NIN + NH */

/* LDS layout (bytes) */
#define WBUF_BYTES (32 * KTOT * 2)          /* 98304: 32 gate rows x 1536 K, bf16, swizzled */
#define ABUF_OFF   WBUF_BYTES
#define ABUF_BYTES (32 * 512 * 2)           /* 32768: 32 x 512 stage, bf16, swizzled */
#define GBUF_OFF   (ABUF_OFF + ABUF_BYTES)  /* 131072 */
#define GBUF_BYTES (32 * 33 * 4)            /* 4224: gate exchange, +1 pad */
#define SMEM_BYTES (GBUF_OFF + GBUF_BYTES)  /* 135296 */

__device__ __forceinline__ float sigmoid_f(float x) {
    return 1.0f / (1.0f + __expf(-x));
}
__device__ __forceinline__ float tanh_f(float x) {
    return 1.0f - 2.0f / (__expf(2.0f * x) + 1.0f);
}

/* agent-scope (sc1) coherent 16B load as two u64 atomics: bypasses stale L1/L2,
   NO whole-cache buffer_inv (the round-5 killer). */
__device__ __forceinline__ f32x4_t coh_load4(const float* p) {
    union { u64 q[2]; f32x4_t v; } u;
    u.q[0] = __hip_atomic_load((const u64*)p,       __ATOMIC_RELAXED, __HIP_MEMORY_SCOPE_AGENT);
    u.q[1] = __hip_atomic_load((const u64*)(p + 2), __ATOMIC_RELAXED, __HIP_MEMORY_SCOPE_AGENT);
    return u.v;
}

/* convert 4 fp32 -> bf16x4 and store swizzled into the 32x512 stage tile */
__device__ __forceinline__ void stage4(char* abuf, int c, f32x4_t v) {
    const int r  = c >> 7;       /* row 0..31 */
    const int kc = c & 127;      /* 4-col chunk */
    union { bf16x4_t b; u32x2_t w; } cv;
    cv.b[0] = (bf16_t)v[0]; cv.b[1] = (bf16_t)v[1];
    cv.b[2] = (bf16_t)v[2]; cv.b[3] = (bf16_t)v[3];
    const unsigned byte = ((unsigned)(r * 1024 + kc * 8)) ^ ((unsigned)((r & 7) << 4));
    *reinterpret_cast<u32x2_t*>(abuf + byte) = cv.w;
}

__global__ void flag_init(int* flags) {
    flags[threadIdx.x] = 0;   /* 256 ints = 1 KB at d_ws+0 */
}

__global__ void __launch_bounds__(256, 1)
lstm_fused(const float* __restrict__ xs, const float* __restrict__ h0,
           const float* __restrict__ c0, const float* __restrict__ Wih,
           const float* __restrict__ Whh, const float* __restrict__ bih,
           const float* __restrict__ bhh, float* __restrict__ out,
           int* __restrict__ flags)
{
    extern __shared__ char smem[];
    char* abuf = smem + ABUF_OFF;

    const int tid = threadIdx.x;
    const int bid = blockIdx.x;
    const int bt  = bid & 1;       /* batch group: 32 batches */
    const int ht  = bid >> 1;      /* hidden tile: 8 units (0..127) */
    int* gflags = flags + bt * 128;
    const int myslot = bid >> 1;

    /* ---- stage weight slice into LDS: rows = 4 gates x 8 units, K = [x | h] ---- */
    {
        const int lr = tid >> 3;                 /* local row 0..31 */
        const int t8 = tid & 7;
        const int g  = lr >> 3;
        const int u  = lr & 7;
        const int R  = g * NH + ht * 8 + u;      /* global gate row in [0,4096) */
        const unsigned rowbase = (unsigned)lr * (KTOT * 2);
        const unsigned swz = (unsigned)((lr & 7) << 4);
        #pragma unroll 4
        for (int j = 0; j < 48; ++j) {
            const int kc = t8 + j * 8;           /* float4 chunk 0..383 */
            const int k  = kc * 4;
            f32x4_t w;
            if (k < NIN) w = *reinterpret_cast<const f32x4_t*>(Wih + (size_t)R * NIN + k);
            else         w = *reinterpret_cast<const f32x4_t*>(Whh + (size_t)R * NH + (k - NIN));
            union { bf16x4_t b; u32x2_t v; } cv;
            cv.b[0] = (bf16_t)w[0]; cv.b[1] = (bf16_t)w[1];
            cv.b[2] = (bf16_t)w[2]; cv.b[3] = (bf16_t)w[3];
            const unsigned byte = (rowbase + (unsigned)(k * 2)) ^ swz;
            *reinterpret_cast<u32x2_t*>(smem + byte) = cv.v;
        }
    }

    /* ---- per-thread owned cell state: (batch em, unit eu) ---- */
    const int em = tid >> 3;            /* 0..31 */
    const int eu = tid & 7;             /* 0..7  */
    const int gb = bt * 32 + em;        /* global batch */
    const int gj = ht * 8 + eu;         /* global hidden idx */
    float c_reg = c0[(size_t)gb * NH + gj];

    /* ---- MFMA fragment constants (2x2 wave tiling of 32x32 output) ---- */
    const int lane = tid & 63;
    const int wid  = tid >> 6;
    const int mi   = wid >> 1;                       /* M tile (batches) */
    const int ni   = wid & 1;                        /* N tile (gate rows) */
    const int nloc = ni * 16 + (lane & 15);          /* B-col = local gate row */
    const int arow = mi * 16 + (lane & 15);          /* A-row = local batch */
    const int kg   = (lane >> 4) * 8;                /* k sub-offset per 16-lane group */
    const unsigned aswz  = (unsigned)((arow & 7) << 4);
    const unsigned bswz  = (unsigned)((nloc & 7) << 4);
    const unsigned abase = (unsigned)(arow * 1024 + kg * 2);

    float bias_r;
    {
        const int g = nloc >> 3, u = nloc & 7;
        const int N = g * NH + ht * 8 + u;
        bias_r = bih[N] + bhh[N];
    }
    float* gbuf = reinterpret_cast<float*>(smem + GBUF_OFF);

    /* ---- prefetch x_0 into registers (plain loads; L2 now stays warm) ---- */
    f32x4_t xr[16];
    {
        const float* xbase = xs + (size_t)(bt * 32) * NIN;
        #pragma unroll
        for (int i = 0; i < 16; ++i) {
            const int c = tid + i * 256;
            xr[i] = *reinterpret_cast<const f32x4_t*>(xbase + (size_t)(c >> 7) * NIN + (c & 127) * 4);
        }
    }

    for (int t = 0; t < NSTEPS; ++t) {
        /* h source: out[t-1] (fp32) for t>0, else h0. Own group's rows only.
           Coherent (sc1) loads — written cross-XCD with sc1 stores last step. */
        const float* hsrc = t ? (out + ((size_t)(t - 1) * NB + bt * 32) * NH)
                              : (h0 + (size_t)(bt * 32) * NH);

        f32x4_t hA[16], hB[16];
        #pragma unroll
        for (int i = 0; i < 16; ++i) {
            const int c = tid + i * 256;
            hA[i] = coh_load4(hsrc + (size_t)(c >> 7) * NH + (c & 127) * 4);
        }
        #pragma unroll
        for (int i = 0; i < 16; ++i) {
            const int c = tid + i * 256;
            hB[i] = coh_load4(hsrc + (size_t)(c >> 7) * NH + 512 + (c & 127) * 4);
        }

        f32x4_t acc = { bias_r, bias_r, bias_r, bias_r };

        /* ===== phase 0: x_t ===== */
        __syncthreads();                        /* S1: abuf free (prev step done) */
        #pragma unroll
        for (int i = 0; i < 16; ++i) stage4(abuf, tid + i * 256, xr[i]);
        __syncthreads();                        /* S2 */
        {
            const unsigned bbase = (unsigned)(nloc * (KTOT * 2) + kg * 2);
            #pragma unroll
            for (int kk = 0; kk < 16; ++kk) {
                bf16x8_t af  = *reinterpret_cast<const bf16x8_t*>(abuf + ((abase + kk * 64) ^ aswz));
                bf16x8_t bfr = *reinterpret_cast<const bf16x8_t*>(smem + ((bbase + kk * 64) ^ bswz));
                acc = __builtin_amdgcn_mfma_f32_16x16x32_bf16(af, bfr, acc, 0, 0, 0);
            }
        }
        /* prefetch x_{t+1}: covered by phases 1-2 + gate math + barrier */
        if (t + 1 < NSTEPS) {
            const float* xbase = xs + ((size_t)(t + 1) * NB + bt * 32) * NIN;
            #pragma unroll
            for (int i = 0; i < 16; ++i) {
                const int c = tid + i * 256;
                xr[i] = *reinterpret_cast<const f32x4_t*>(xbase + (size_t)(c >> 7) * NIN + (c & 127) * 4);
            }
        }

        /* ===== phase 1: h cols [0,512) ===== */
        __syncthreads();                        /* S3: phase-0 mfma done */
        #pragma unroll
        for (int i = 0; i < 16; ++i) stage4(abuf, tid + i * 256, hA[i]);
        __syncthreads();                        /* S4 */
        {
            const unsigned bbase = (unsigned)(nloc * (KTOT * 2) + (512 + kg) * 2);
            #pragma unroll
            for (int kk = 0; kk < 16; ++kk) {
                bf16x8_t af  = *reinterpret_cast<const bf16x8_t*>(abuf + ((abase + kk * 64) ^ aswz));
                bf16x8_t bfr = *reinterpret_cast<const bf16x8_t*>(smem + ((bbase + kk * 64) ^ bswz));
                acc = __builtin_amdgcn_mfma_f32_16x16x32_bf16(af, bfr, acc, 0, 0, 0);
            }
        }

        /* ===== phase 2: h cols [512,1024) ===== */
        __syncthreads();                        /* S5 */
        #pragma unroll
        for (int i = 0; i < 16; ++i) stage4(abuf, tid + i * 256, hB[i]);
        __syncthreads();                        /* S6 */
        {
            const unsigned bbase = (unsigned)(nloc * (KTOT * 2) + (1024 + kg) * 2);
            #pragma unroll
            for (int kk = 0; kk < 16; ++kk) {
                bf16x8_t af  = *reinterpret_cast<const bf16x8_t*>(abuf + ((abase + kk * 64) ^ aswz));
                bf16x8_t bfr = *reinterpret_cast<const bf16x8_t*>(smem + ((bbase + kk * 64) ^ bswz));
                acc = __builtin_amdgcn_mfma_f32_16x16x32_bf16(af, bfr, acc, 0, 0, 0);
            }
        }

        /* ---- exchange gates via LDS: D layout col=lane&15, row=(lane>>4)*4+reg ---- */
        {
            const int mbase = mi * 16 + ((lane >> 4) << 2);
            #pragma unroll
            for (int r = 0; r < 4; ++r)
                gbuf[(mbase + r) * 33 + nloc] = acc[r];
        }
        __syncthreads();                        /* S7 */

        /* ---- elementwise gate math; each thread owns (em, eu) ---- */
        {
            const float gi = gbuf[em * 33 +      eu];
            const float gf = gbuf[em * 33 +  8 + eu];
            const float gc = gbuf[em * 33 + 16 + eu];
            const float go = gbuf[em * 33 + 24 + eu];
            const float i_ = sigmoid_f(gi);
            const float f_ = sigmoid_f(gf);
            const float g_ = tanh_f(gc);
            const float o_ = sigmoid_f(go);
            c_reg = f_ * c_reg + i_ * g_;
            const float h_ = o_ * tanh_f(c_reg);
            /* sc1 store: lands at the coherence point, no dirty L2 line */
            __hip_atomic_store((unsigned*)&out[((size_t)t * NB + gb) * NH + gj],
                               __float_as_uint(h_),
                               __ATOMIC_RELAXED, __HIP_MEMORY_SCOPE_AGENT);
        }

        /* ---- group barrier: per-wave store-drain + monotonic flags (tag t+1).
           NO __threadfence (no buffer_wbl2 / buffer_inv). ---- */
        if (t + 1 < NSTEPS) {
            /* every wave drains its own sc1 stores to the coherence point */
            asm volatile("s_waitcnt vmcnt(0)" ::: "memory");
            __syncthreads();                    /* S8: all waves drained */
            if (tid == 0)
                __hip_atomic_store(&gflags[myslot], t + 1,
                                   __ATOMIC_RELAXED, __HIP_MEMORY_SCOPE_AGENT);
            if (tid < 128) {
                int spins = 0;
                while (__hip_atomic_load(&gflags[tid], __ATOMIC_RELAXED,
                                         __HIP_MEMORY_SCOPE_AGENT) < t + 1) {
                    __builtin_amdgcn_s_sleep(1);
                    if (++spins > (1 << 18)) break;   /* bounded: fail loud, not hang */
                }
            }
            __syncthreads();                    /* S9: all 128 producers observed */
        }
    }
}

extern "C" void kernel_launch(void* const* d_in, const int* in_sizes, int n_in,
                              void* d_out, int out_size, void* d_ws, size_t ws_size,
                              hipStream_t stream)
{
    const float* xs  = (const float*)d_in[0];
    const float* h0  = (const float*)d_in[1];
    const float* c0  = (const float*)d_in[2];
    const float* Wih = (const float*)d_in[3];
    const float* Whh = (const float*)d_in[4];
    const float* bih = (const float*)d_in[5];
    const float* bhh = (const float*)d_in[6];
    float* out = (float*)d_out;

    int* flags = (int*)d_ws;   /* 1 KB at offset 0 — in-bounds for any ws_size */

    flag_init<<<1, 256, 0, stream>>>(flags);

    (void)hipFuncSetAttribute((const void*)lstm_fused,
                              hipFuncAttributeMaxDynamicSharedMemorySize,
                              SMEM_BYTES);

    void* args[] = { &xs, &h0, &c0, &Wih, &Whh, &bih, &bhh, &out, &flags };
    hipError_t e = hipLaunchCooperativeKernel((void*)lstm_fused, dim3(256), dim3(256),
                                              args, (unsigned)SMEM_BYTES, stream);
    if (e != hipSuccess) {
        (void)hipGetLastError();   /* clear sticky error, then plain launch:    */
        /* grid=256=#CUs and 132KB LDS force 1 block/CU -> co-resident anyway. */
        lstm_fused<<<dim3(256), dim3(256), SMEM_BYTES, stream>>>(
            xs, h0, c0, Wih, Whh, bih, bhh, out, flags);
    }
}

// Round 7
// 5288.939 us; speedup vs baseline: 3.7527x; 1.0111x over previous
//
#include <hip/hip_runtime.h>
#include <hip/hip_bf16.h>

typedef __bf16 bf16_t;
typedef __bf16 bf16x8_t __attribute__((ext_vector_type(8)));
typedef __bf16 bf16x4_t __attribute__((ext_vector_type(4)));
typedef float  f32x4_t  __attribute__((ext_vector_type(4)));
typedef unsigned int u32x4_t __attribute__((ext_vector_type(4)));
typedef unsigned int u32x2_t __attribute__((ext_vector_type(2)));
typedef unsigned long long u64;

#define NSTEPS 512
#define NB     64
#define NIN    512
#define NH     1024
#define KTOT   1536

/* LDS layout (bytes) */
#define WBUF_BYTES (32 * KTOT * 2)          /* 98304 */
#define ABUF_OFF   WBUF_BYTES
#define ABUF_BYTES (32 * 512 * 2)           /* 32768 */
#define GBUF_OFF   (ABUF_OFF + ABUF_BYTES)
#define GBUF_BYTES (32 * 33 * 4)
#define SMEM_BYTES (GBUF_OFF + GBUF_BYTES)  /* 135296 */

/* ws: [0,2K) flags (region 0 = real, region 1 = diag); [4K,260K) bf16 h ping-pong */
#define WS_HBUF_OFF  4096
#define WS_NEED_BF16 (WS_HBUF_OFF + 2 * NB * NH * 2)

/* raw barrier WITHOUT vmcnt drain: LDS-consistent only (verified 8-phase pattern) */
#define BARRIER_LDS() do {                                      \
    asm volatile("s_waitcnt lgkmcnt(0)" ::: "memory");          \
    __builtin_amdgcn_s_barrier();                               \
    __builtin_amdgcn_sched_barrier(0);                          \
} while (0)

__device__ __forceinline__ float sigmoid_f(float x) { return 1.0f / (1.0f + __expf(-x)); }
__device__ __forceinline__ float tanh_f(float x)    { return 1.0f - 2.0f / (__expf(2.0f * x) + 1.0f); }

/* agent-scope (sc1) coherent 16B loads — bypass stale L1/L2, no cache-wide inv */
__device__ __forceinline__ f32x4_t coh_load_f4(const float* p) {
    union { u64 q[2]; f32x4_t v; } u;
    u.q[0] = __hip_atomic_load((const u64*)p,       __ATOMIC_RELAXED, __HIP_MEMORY_SCOPE_AGENT);
    u.q[1] = __hip_atomic_load((const u64*)(p + 2), __ATOMIC_RELAXED, __HIP_MEMORY_SCOPE_AGENT);
    return u.v;
}
__device__ __forceinline__ u32x4_t coh_load_u4(const bf16_t* p) {
    union { u64 q[2]; u32x4_t v; } u;
    u.q[0] = __hip_atomic_load((const u64*)p,     __ATOMIC_RELAXED, __HIP_MEMORY_SCOPE_AGENT);
    u.q[1] = __hip_atomic_load((const u64*)p + 1, __ATOMIC_RELAXED, __HIP_MEMORY_SCOPE_AGENT);
    return u.v;
}

/* fp32x4 -> bf16x4, swizzled store into 32x512 stage tile (chunk c: r=c>>7, kc=c&127) */
__device__ __forceinline__ void stage4(char* abuf, int c, f32x4_t v) {
    const int r = c >> 7, kc = c & 127;
    union { bf16x4_t b; u32x2_t w; } cv;
    cv.b[0] = (bf16_t)v[0]; cv.b[1] = (bf16_t)v[1];
    cv.b[2] = (bf16_t)v[2]; cv.b[3] = (bf16_t)v[3];
    const unsigned byte = ((unsigned)(r * 1024 + kc * 8)) ^ ((unsigned)((r & 7) << 4));
    *reinterpret_cast<u32x2_t*>(abuf + byte) = cv.w;
}
/* straight 16B bf16 copy, swizzled (chunk c: r=c>>6, kc=c&63) */
__device__ __forceinline__ void stage16(char* abuf, int c, u32x4_t v) {
    const int r = c >> 6, kc = c & 63;
    const unsigned byte = ((unsigned)(r * 1024 + kc * 16)) ^ ((unsigned)((r & 7) << 4));
    *reinterpret_cast<u32x4_t*>(abuf + byte) = v;
}

__global__ void flag_init(int* flags) { flags[threadIdx.x] = 0; }  /* 512 ints */

template<int VAR, bool BF16X>
__global__ void __launch_bounds__(256, 1)
lstm_fused(const float* __restrict__ xs, const float* __restrict__ h0,
           const float* __restrict__ c0, const float* __restrict__ Wih,
           const float* __restrict__ Whh, const float* __restrict__ bih,
           const float* __restrict__ bhh, float* __restrict__ out,
           bf16_t* __restrict__ hbA, bf16_t* __restrict__ hbB,
           int* __restrict__ flags)
{
    extern __shared__ char smem[];
    char* abuf = smem + ABUF_OFF;

    const int tid = threadIdx.x;
    const int bid = blockIdx.x;
    const int bt  = bid & 1;
    const int ht  = bid >> 1;
    int* gflags = flags + VAR * 256 + bt * 128;
    const int myslot = bid >> 1;

    /* ---- weights -> LDS ---- */
    {
        const int lr = tid >> 3, t8 = tid & 7;
        const int R  = (lr >> 3) * NH + ht * 8 + (lr & 7);
        const unsigned rowbase = (unsigned)lr * (KTOT * 2);
        const unsigned swz = (unsigned)((lr & 7) << 4);
        #pragma unroll 4
        for (int j = 0; j < 48; ++j) {
            const int k = (t8 + j * 8) * 4;
            f32x4_t w;
            if (k < NIN) w = *reinterpret_cast<const f32x4_t*>(Wih + (size_t)R * NIN + k);
            else         w = *reinterpret_cast<const f32x4_t*>(Whh + (size_t)R * NH + (k - NIN));
            union { bf16x4_t b; u32x2_t v; } cv;
            cv.b[0] = (bf16_t)w[0]; cv.b[1] = (bf16_t)w[1];
            cv.b[2] = (bf16_t)w[2]; cv.b[3] = (bf16_t)w[3];
            *reinterpret_cast<u32x2_t*>(smem + ((rowbase + (unsigned)(k * 2)) ^ swz)) = cv.v;
        }
    }

    /* ---- h0 -> bf16 ping buffer (own slice) ---- */
    if (BF16X) {
        const int q   = (bid >> 1) * 256 + tid;            /* 0..32767 in group */
        const int idx = (bt * 32 + (q >> 10)) * NH + (q & 1023);
        union { bf16_t b; unsigned short s; } cv; cv.b = (bf16_t)h0[idx];
        __hip_atomic_store((unsigned short*)&hbA[idx], cv.s,
                           __ATOMIC_RELAXED, __HIP_MEMORY_SCOPE_AGENT);
    }

    const int em = tid >> 3, eu = tid & 7;
    const int gb = bt * 32 + em, gj = ht * 8 + eu;
    float c_reg = c0[(size_t)gb * NH + gj];

    const int lane = tid & 63, wid = tid >> 6;
    const int mi = wid >> 1, ni = wid & 1;
    const int nloc = ni * 16 + (lane & 15);
    const int arow = mi * 16 + (lane & 15);
    const int kg   = (lane >> 4) * 8;
    const unsigned aswz  = (unsigned)((arow & 7) << 4);
    const unsigned bswz  = (unsigned)((nloc & 7) << 4);
    const unsigned abase = (unsigned)(arow * 1024 + kg * 2);

    float bias_r;
    {
        const int N = (nloc >> 3) * NH + ht * 8 + (nloc & 7);
        bias_r = bih[N] + bhh[N];
    }
    float* gbuf = reinterpret_cast<float*>(smem + GBUF_OFF);

    auto mfma_phase = [&](unsigned koff, f32x4_t a) -> f32x4_t {
        const unsigned bbase = (unsigned)(nloc * (KTOT * 2) + (koff + kg) * 2);
        #pragma unroll
        for (int kk = 0; kk < 16; ++kk) {
            bf16x8_t af  = *reinterpret_cast<const bf16x8_t*>(abuf + ((abase + kk * 64) ^ aswz));
            bf16x8_t bfr = *reinterpret_cast<const bf16x8_t*>(smem + ((bbase + kk * 64) ^ bswz));
            a = __builtin_amdgcn_mfma_f32_16x16x32_bf16(af, bfr, a, 0, 0, 0);
        }
        return a;
    };

    /* ---- x_0 loads ---- */
    f32x4_t xr[16];
    {
        const float* xbase = xs + (size_t)(bt * 32) * NIN;
        #pragma unroll
        for (int i = 0; i < 16; ++i) {
            const int c = tid + i * 256;
            xr[i] = *reinterpret_cast<const f32x4_t*>(xbase + (size_t)(c >> 7) * NIN + (c & 127) * 4);
        }
    }

    /* prologue publish: h_0 ready (tag 1) */
    asm volatile("s_waitcnt vmcnt(0)" ::: "memory");
    __syncthreads();
    if (tid == 0)
        __hip_atomic_store(&gflags[myslot], 1, __ATOMIC_RELAXED, __HIP_MEMORY_SCOPE_AGENT);

    /* x-GEMM(0) into accx */
    #pragma unroll
    for (int i = 0; i < 16; ++i) stage4(abuf, tid + i * 256, xr[i]);
    BARRIER_LDS();
    f32x4_t accx = { bias_r, bias_r, bias_r, bias_r };
    accx = mfma_phase(0, accx);

    for (int t = 0; t < NSTEPS; ++t) {
        /* wait h_t published by all 128 producers of this group */
        if (VAR == 0) {
            if (tid < 128) {
                int spins = 0;
                while (__hip_atomic_load(&gflags[tid], __ATOMIC_RELAXED,
                                         __HIP_MEMORY_SCOPE_AGENT) < t + 1) {
                    __builtin_amdgcn_s_sleep(1);
                    if (++spins > (1 << 20)) break;
                }
            }
        }
        __builtin_amdgcn_s_barrier();          /* all threads: h_t visible */
        __builtin_amdgcn_sched_barrier(0);

        /* issue h loads first, then x_{t+1} (in-order vmcnt: h waits don't wait x) */
        u32x4_t hh16[16];                      /* BF16X path */
        f32x4_t hf[32];                        /* fp32 path  */
        if (BF16X) {
            const bf16_t* hsrc = ((t & 1) ? hbB : hbA) + (size_t)(bt * 32) * NH;
            #pragma unroll
            for (int i = 0; i < 16; ++i) {
                const int c = tid + (i & 7) * 256;         /* half: i<8 -> A, else B */
                hh16[i] = coh_load_u4(hsrc + (size_t)(c >> 6) * NH + (i < 8 ? 0 : 512) + (c & 63) * 8);
            }
        } else {
            const float* hsrc = t ? (out + ((size_t)(t - 1) * NB + bt * 32) * NH)
                                  : (h0 + (size_t)(bt * 32) * NH);
            #pragma unroll
            for (int i = 0; i < 32; ++i) {
                const int c = tid + (i & 15) * 256;
                hf[i] = coh_load_f4(hsrc + (size_t)(c >> 7) * NH + (i < 16 ? 0 : 512) + (c & 127) * 4);
            }
        }
        if (t + 1 < NSTEPS) {
            const float* xbase = xs + ((size_t)(t + 1) * NB + bt * 32) * NIN;
            #pragma unroll
            for (int i = 0; i < 16; ++i) {
                const int c = tid + i * 256;
                xr[i] = *reinterpret_cast<const f32x4_t*>(xbase + (size_t)(c >> 7) * NIN + (c & 127) * 4);
            }
        }

        f32x4_t acc = accx;                    /* bias + x part, precomputed */

        BARRIER_LDS();                         /* B1: abuf free (x-MFMA reads done) */
        if (BF16X) {
            #pragma unroll
            for (int i = 0; i < 8; ++i)  stage16(abuf, tid + i * 256, hh16[i]);
        } else {
            #pragma unroll
            for (int i = 0; i < 16; ++i) stage4(abuf, tid + i * 256, hf[i]);
        }
        BARRIER_LDS();                         /* B2 */
        acc = mfma_phase(512, acc);

        BARRIER_LDS();                         /* B3 */
        if (BF16X) {
            #pragma unroll
            for (int i = 8; i < 16; ++i) stage16(abuf, tid + (i - 8) * 256, hh16[i]);
        } else {
            #pragma unroll
            for (int i = 16; i < 32; ++i) stage4(abuf, tid + (i - 16) * 256, hf[i]);
        }
        BARRIER_LDS();                         /* B4 */
        acc = mfma_phase(1024, acc);

        /* gate exchange (D: col=lane&15, row=(lane>>4)*4+reg) */
        {
            const int mbase = mi * 16 + ((lane >> 4) << 2);
            #pragma unroll
            for (int r = 0; r < 4; ++r)
                gbuf[(mbase + r) * 33 + nloc] = acc[r];
        }
        BARRIER_LDS();                         /* B5 */

        {
            const float gi = gbuf[em * 33 +      eu];
            const float gf = gbuf[em * 33 +  8 + eu];
            const float gc = gbuf[em * 33 + 16 + eu];
            const float go = gbuf[em * 33 + 24 + eu];
            const float i_ = sigmoid_f(gi);
            const float f_ = sigmoid_f(gf);
            const float g_ = tanh_f(gc);
            const float o_ = sigmoid_f(go);
            c_reg = f_ * c_reg + i_ * g_;
            const float h_ = o_ * tanh_f(c_reg);
            if (BF16X) {
                out[((size_t)t * NB + gb) * NH + gj] = h_;         /* plain fp32 */
                if (t + 1 < NSTEPS) {
                    bf16_t* dst = ((t + 1) & 1) ? hbB : hbA;
                    union { bf16_t b; unsigned short s; } cv; cv.b = (bf16_t)h_;
                    __hip_atomic_store((unsigned short*)&dst[(size_t)gb * NH + gj],
                                       cv.s, __ATOMIC_RELAXED, __HIP_MEMORY_SCOPE_AGENT);
                }
            } else {
                __hip_atomic_store((unsigned*)&out[((size_t)t * NB + gb) * NH + gj],
                                   __float_as_uint(h_),
                                   __ATOMIC_RELAXED, __HIP_MEMORY_SCOPE_AGENT);
            }
        }

        if (t + 1 < NSTEPS) {
            asm volatile("s_waitcnt vmcnt(0)" ::: "memory");  /* h stores at coherence pt */
            BARRIER_LDS();                     /* B6: all waves drained */
            if (tid == 0)
                __hip_atomic_store(&gflags[myslot], t + 2,
                                   __ATOMIC_RELAXED, __HIP_MEMORY_SCOPE_AGENT);
            /* x-GEMM(t+1): fills the barrier-skew window, off the h critical path */
            #pragma unroll
            for (int i = 0; i < 16; ++i) stage4(abuf, tid + i * 256, xr[i]);
            BARRIER_LDS();                     /* B7 */
            accx = f32x4_t{ bias_r, bias_r, bias_r, bias_r };
            accx = mfma_phase(0, accx);
        }
    }
}

extern "C" void kernel_launch(void* const* d_in, const int* in_sizes, int n_in,
                              void* d_out, int out_size, void* d_ws, size_t ws_size,
                              hipStream_t stream)
{
    const float* xs  = (const float*)d_in[0];
    const float* h0  = (const float*)d_in[1];
    const float* c0  = (const float*)d_in[2];
    const float* Wih = (const float*)d_in[3];
    const float* Whh = (const float*)d_in[4];
    const float* bih = (const float*)d_in[5];
    const float* bhh = (const float*)d_in[6];
    float* out = (float*)d_out;

    int*    flags = (int*)d_ws;
    bf16_t* hbA   = (bf16_t*)((char*)d_ws + WS_HBUF_OFF);
    bf16_t* hbB   = hbA + (size_t)NB * NH;
    const bool bf16x = (ws_size >= (size_t)WS_NEED_BF16);

    flag_init<<<1, 512, 0, stream>>>(flags);

    void* args[] = { &xs, &h0, &c0, &Wih, &Whh, &bih, &bhh, &out, &hbA, &hbB, &flags };

    if (bf16x) {
        (void)hipFuncSetAttribute(reinterpret_cast<const void*>(lstm_fused<1, true>),
                                  hipFuncAttributeMaxDynamicSharedMemorySize, SMEM_BYTES);
        (void)hipFuncSetAttribute(reinterpret_cast<const void*>(lstm_fused<0, true>),
                                  hipFuncAttributeMaxDynamicSharedMemorySize, SMEM_BYTES);
        /* diagnostic: no-barrier variant first (junk output, fully overwritten) */
        lstm_fused<1, true><<<dim3(256), dim3(256), SMEM_BYTES, stream>>>(
            xs, h0, c0, Wih, Whh, bih, bhh, out, hbA, hbB, flags);
        hipError_t e = hipLaunchCooperativeKernel((void*)lstm_fused<0, true>,
                                                  dim3(256), dim3(256), args,
                                                  (unsigned)SMEM_BYTES, stream);
        if (e != hipSuccess) {
            (void)hipGetLastError();
            lstm_fused<0, true><<<dim3(256), dim3(256), SMEM_BYTES, stream>>>(
                xs, h0, c0, Wih, Whh, bih, bhh, out, hbA, hbB, flags);
        }
    } else {
        (void)hipFuncSetAttribute(reinterpret_cast<const void*>(lstm_fused<1, false>),
                                  hipFuncAttributeMaxDynamicSharedMemorySize, SMEM_BYTES);
        (void)hipFuncSetAttribute(reinterpret_cast<const void*>(lstm_fused<0, false>),
                                  hipFuncAttributeMaxDynamicSharedMemorySize, SMEM_BYTES);
        lstm_fused<1, false><<<dim3(256), dim3(256), SMEM_BYTES, stream>>>(
            xs, h0, c0, Wih, Whh, bih, bhh, out, hbA, hbB, flags);
        hipError_t e = hipLaunchCooperativeKernel((void*)lstm_fused<0, false>,
                                                  dim3(256), dim3(256), args,
                                                  (unsigned)SMEM_BYTES, stream);
        if (e != hipSuccess) {
            (void)hipGetLastError();
            lstm_fused<0, false><<<dim3(256), dim3(256), SMEM_BYTES, stream>>>(
                xs, h0, c0, Wih, Whh, bih, bhh, out, hbA, hbB, flags);
        }
    }
}

// Round 8
// 3000.139 us; speedup vs baseline: 6.6157x; 1.7629x over previous
//
#include <hip/hip_runtime.h>
#include <hip/hip_bf16.h>

typedef __bf16 bf16_t;
typedef __bf16 bf16x8_t __attribute__((ext_vector_type(8)));
typedef __bf16 bf16x4_t __attribute__((ext_vector_type(4)));
typedef float  f32x4_t  __attribute__((ext_vector_type(4)));
typedef unsigned int u32x4_t __attribute__((ext_vector_type(4)));
typedef unsigned int u32x2_t __attribute__((ext_vector_type(2)));
typedef unsigned long long u64;

#define NSTEPS 512
#define NB     64
#define NIN    512
#define NH     1024
#define KTOT   1536
#define NTHR   512

/* LDS layout (bytes) */
#define WBUF_BYTES (32 * KTOT * 2)          /* 98304: 32 gate rows x 1536 K */
#define ABUF_OFF   WBUF_BYTES
#define ABUF_BYTES (32 * 512 * 2)           /* 32768: 32 x 512 stage */
#define GBUF_OFF   (ABUF_OFF + ABUF_BYTES)  /* 131072 */
#define GBUF_BYTES (2 * 32 * 33 * 4)        /* 8448: 2 K-planes of gates */
#define SMEM_BYTES (GBUF_OFF + GBUF_BYTES)  /* 139520 */

/* ws: [0,1K) flags; [4K,260K) bf16 h ping-pong */
#define WS_HBUF_OFF  4096
#define WS_NEED_BF16 (WS_HBUF_OFF + 2 * NB * NH * 2)

/* raw barrier WITHOUT vmcnt drain (LDS-consistent only) */
#define BARRIER_LDS() do {                                      \
    asm volatile("s_waitcnt lgkmcnt(0)" ::: "memory");          \
    __builtin_amdgcn_s_barrier();                               \
    __builtin_amdgcn_sched_barrier(0);                          \
} while (0)

__device__ __forceinline__ float sigmoid_f(float x) { return 1.0f / (1.0f + __expf(-x)); }
__device__ __forceinline__ float tanh_f(float x)    { return 1.0f - 2.0f / (__expf(2.0f * x) + 1.0f); }

/* agent-scope (sc1) coherent 16B loads — bypass stale L1/L2, no cache-wide inv */
__device__ __forceinline__ f32x4_t coh_load_f4(const float* p) {
    union { u64 q[2]; f32x4_t v; } u;
    u.q[0] = __hip_atomic_load((const u64*)p,       __ATOMIC_RELAXED, __HIP_MEMORY_SCOPE_AGENT);
    u.q[1] = __hip_atomic_load((const u64*)(p + 2), __ATOMIC_RELAXED, __HIP_MEMORY_SCOPE_AGENT);
    return u.v;
}
__device__ __forceinline__ u32x4_t coh_load_u4(const bf16_t* p) {
    union { u64 q[2]; u32x4_t v; } u;
    u.q[0] = __hip_atomic_load((const u64*)p,     __ATOMIC_RELAXED, __HIP_MEMORY_SCOPE_AGENT);
    u.q[1] = __hip_atomic_load((const u64*)p + 1, __ATOMIC_RELAXED, __HIP_MEMORY_SCOPE_AGENT);
    return u.v;
}

/* fp32x4 -> bf16x4 swizzled store into 32x512 stage (chunk c: r=c>>7, kc=c&127) */
__device__ __forceinline__ void stage4(char* abuf, int c, f32x4_t v) {
    const int r = c >> 7, kc = c & 127;
    union { bf16x4_t b; u32x2_t w; } cv;
    cv.b[0] = (bf16_t)v[0]; cv.b[1] = (bf16_t)v[1];
    cv.b[2] = (bf16_t)v[2]; cv.b[3] = (bf16_t)v[3];
    const unsigned byte = ((unsigned)(r * 1024 + kc * 8)) ^ ((unsigned)((r & 7) << 4));
    *reinterpret_cast<u32x2_t*>(abuf + byte) = cv.w;
}
/* straight 16B bf16 copy, swizzled (chunk c: r=c>>6, kc=c&63) */
__device__ __forceinline__ void stage16(char* abuf, int c, u32x4_t v) {
    const int r = c >> 6, kc = c & 63;
    const unsigned byte = ((unsigned)(r * 1024 + kc * 16)) ^ ((unsigned)((r & 7) << 4));
    *reinterpret_cast<u32x4_t*>(abuf + byte) = v;
}

__global__ void flag_init(int* flags) { flags[threadIdx.x] = 0; }  /* 256 ints */

template<bool BF16X>
__global__ void __launch_bounds__(NTHR, 1)
lstm_fused(const float* __restrict__ xs, const float* __restrict__ h0,
           const float* __restrict__ c0, const float* __restrict__ Wih,
           const float* __restrict__ Whh, const float* __restrict__ bih,
           const float* __restrict__ bhh, float* __restrict__ out,
           bf16_t* __restrict__ hbA, bf16_t* __restrict__ hbB,
           int* __restrict__ flags)
{
    extern __shared__ char smem[];
    char*  abuf = smem + ABUF_OFF;
    float* gbuf = reinterpret_cast<float*>(smem + GBUF_OFF);

    const int tid = threadIdx.x;
    const int bid = blockIdx.x;
    const int bt  = bid & 1;       /* batch group: 32 batches */
    const int ht  = bid >> 1;      /* hidden tile: 8 units */
    int* gflags = flags + bt * 128;
    const int myslot = bid >> 1;

    /* ---- weights -> LDS (512 threads) ---- */
    {
        const int lr  = tid >> 4;                 /* row 0..31 */
        const int t16 = tid & 15;
        const int R   = (lr >> 3) * NH + ht * 8 + (lr & 7);
        const unsigned rowbase = (unsigned)lr * (KTOT * 2);
        const unsigned swz = (unsigned)((lr & 7) << 4);
        #pragma unroll 4
        for (int j = 0; j < 24; ++j) {
            const int k = (t16 + j * 16) * 4;
            f32x4_t w;
            if (k < NIN) w = *reinterpret_cast<const f32x4_t*>(Wih + (size_t)R * NIN + k);
            else         w = *reinterpret_cast<const f32x4_t*>(Whh + (size_t)R * NH + (k - NIN));
            union { bf16x4_t b; u32x2_t v; } cv;
            cv.b[0] = (bf16_t)w[0]; cv.b[1] = (bf16_t)w[1];
            cv.b[2] = (bf16_t)w[2]; cv.b[3] = (bf16_t)w[3];
            *reinterpret_cast<u32x2_t*>(smem + ((rowbase + (unsigned)(k * 2)) ^ swz)) = cv.v;
        }
    }

    /* ---- h0 -> bf16 ping buffer (own group slice; duplicated x2, benign) ---- */
    if (BF16X) {
        const int q   = (bid >> 1) * 256 + (tid & 255);
        const int idx = (bt * 32 + (q >> 10)) * NH + (q & 1023);
        union { bf16_t b; unsigned short s; } cv; cv.b = (bf16_t)h0[idx];
        __hip_atomic_store((unsigned short*)&hbA[idx], cv.s,
                           __ATOMIC_RELAXED, __HIP_MEMORY_SCOPE_AGENT);
    }

    /* ---- cell-state ownership: threads 0..255 ---- */
    const int em = tid >> 3, eu = tid & 7;
    const int gb = bt * 32 + em, gj = ht * 8 + eu;
    float c_reg = 0.0f;
    if (tid < 256) c_reg = c0[(size_t)gb * NH + gj];

    /* ---- wave mapping: 8 waves = 2M x 2N x 2K-split ---- */
    const int lane = tid & 63, wid = tid >> 6;
    const int mi = wid & 1;                /* M tile */
    const int ni = (wid >> 1) & 1;         /* N tile */
    const int ks = wid >> 2;               /* K half (kk parity) */
    const int nloc = ni * 16 + (lane & 15);
    const int arow = mi * 16 + (lane & 15);
    const int kgs  = (lane >> 4) * 8;
    const unsigned aswz  = (unsigned)((arow & 7) << 4);
    const unsigned bswz  = (unsigned)((nloc & 7) << 4);
    const unsigned abase = (unsigned)(arow * 1024 + (lane >> 4) * 16);

    float bias_r = 0.0f;
    if (ks == 0) {
        const int N = (nloc >> 3) * NH + ht * 8 + (nloc & 7);
        bias_r = bih[N] + bhh[N];
    }

    auto mfma_phase = [&](unsigned koff, f32x4_t a) -> f32x4_t {
        const unsigned bbase = (unsigned)(nloc * (KTOT * 2) + (koff + kgs) * 2);
        #pragma unroll
        for (int j = 0; j < 8; ++j) {
            const unsigned kk = (unsigned)(2 * j + ks);
            bf16x8_t af  = *reinterpret_cast<const bf16x8_t*>(abuf + ((abase + kk * 64) ^ aswz));
            bf16x8_t bfr = *reinterpret_cast<const bf16x8_t*>(smem + ((bbase + kk * 64) ^ bswz));
            a = __builtin_amdgcn_mfma_f32_16x16x32_bf16(af, bfr, a, 0, 0, 0);
        }
        return a;
    };

    /* ---- x_0 loads (8 x 16B per thread) ---- */
    f32x4_t xr[8];
    {
        const float* xbase = xs + (size_t)(bt * 32) * NIN;
        #pragma unroll
        for (int i = 0; i < 8; ++i) {
            const int c = tid + i * NTHR;
            xr[i] = *reinterpret_cast<const f32x4_t*>(xbase + (size_t)(c >> 7) * NIN + (c & 127) * 4);
        }
    }

    /* prologue: weights visible + h0 published (tag 1) */
    asm volatile("s_waitcnt vmcnt(0)" ::: "memory");
    __syncthreads();
    if (tid == 0)
        __hip_atomic_store(&gflags[myslot], 1, __ATOMIC_RELAXED, __HIP_MEMORY_SCOPE_AGENT);

    /* x-GEMM(0) */
    #pragma unroll
    for (int i = 0; i < 8; ++i) stage4(abuf, tid + i * NTHR, xr[i]);
    BARRIER_LDS();
    f32x4_t accx = { bias_r, bias_r, bias_r, bias_r };
    accx = mfma_phase(0, accx);

    for (int t = 0; t < NSTEPS; ++t) {
        /* wait h_t published by all 128 producers of this group */
        if (tid < 128) {
            int spins = 0;
            while (__hip_atomic_load(&gflags[tid], __ATOMIC_RELAXED,
                                     __HIP_MEMORY_SCOPE_AGENT) < t + 1) {
                __builtin_amdgcn_s_sleep(1);
                if (++spins > (1 << 20)) break;
            }
        }
        __builtin_amdgcn_s_barrier();          /* h_t visible; prev x-mfma abuf reads done */
        __builtin_amdgcn_sched_barrier(0);

        /* issue h loads, then x_{t+1} (in-order vmcnt: h-waits skip x) */
        u32x4_t hh16[8];                       /* BF16X */
        f32x4_t hf[16];                        /* fp32 fallback */
        if (BF16X) {
            const bf16_t* hsrc = ((t & 1) ? hbB : hbA) + (size_t)(bt * 32) * NH;
            #pragma unroll
            for (int i = 0; i < 8; ++i) {
                const int c = tid + (i & 3) * NTHR;
                hh16[i] = coh_load_u4(hsrc + (size_t)(c >> 6) * NH + (i < 4 ? 0 : 512) + (c & 63) * 8);
            }
        } else {
            const float* hsrc = t ? (out + ((size_t)(t - 1) * NB + bt * 32) * NH)
                                  : (h0 + (size_t)(bt * 32) * NH);
            #pragma unroll
            for (int i = 0; i < 16; ++i) {
                const int c = tid + (i & 7) * NTHR;
                hf[i] = coh_load_f4(hsrc + (size_t)(c >> 7) * NH + (i < 8 ? 0 : 512) + (c & 127) * 4);
            }
        }
        if (t + 1 < NSTEPS) {
            const float* xbase = xs + ((size_t)(t + 1) * NB + bt * 32) * NIN;
            #pragma unroll
            for (int i = 0; i < 8; ++i) {
                const int c = tid + i * NTHR;
                xr[i] = *reinterpret_cast<const f32x4_t*>(xbase + (size_t)(c >> 7) * NIN + (c & 127) * 4);
            }
        }

        f32x4_t acc = accx;                    /* bias(ks0) + x K-half */

        /* stage h half1 (entry barrier protects abuf) */
        if (BF16X) {
            #pragma unroll
            for (int i = 0; i < 4; ++i) stage16(abuf, tid + i * NTHR, hh16[i]);
        } else {
            #pragma unroll
            for (int i = 0; i < 8; ++i) stage4(abuf, tid + i * NTHR, hf[i]);
        }
        BARRIER_LDS();                         /* B2: h1 staged */
        acc = mfma_phase(512, acc);

        BARRIER_LDS();                         /* B3: h1 reads done */
        if (BF16X) {
            #pragma unroll
            for (int i = 4; i < 8; ++i) stage16(abuf, tid + (i - 4) * NTHR, hh16[i]);
        } else {
            #pragma unroll
            for (int i = 8; i < 16; ++i) stage4(abuf, tid + (i - 8) * NTHR, hf[i]);
        }
        BARRIER_LDS();                         /* B4: h2 staged */
        acc = mfma_phase(1024, acc);

        /* gbuf: 2 K-planes (D: col=lane&15, row=(lane>>4)*4+reg) */
        {
            const int mbase = mi * 16 + ((lane >> 4) << 2);
            float* gp = gbuf + ks * (32 * 33);
            #pragma unroll
            for (int r = 0; r < 4; ++r)
                gp[(mbase + r) * 33 + nloc] = acc[r];
        }
        BARRIER_LDS();                         /* B5: gbuf visible */

        if (tid < 256) {
            const float gi = gbuf[em * 33 +      eu] + gbuf[32*33 + em * 33 +      eu];
            const float gf = gbuf[em * 33 +  8 + eu] + gbuf[32*33 + em * 33 +  8 + eu];
            const float gc = gbuf[em * 33 + 16 + eu] + gbuf[32*33 + em * 33 + 16 + eu];
            const float go = gbuf[em * 33 + 24 + eu] + gbuf[32*33 + em * 33 + 24 + eu];
            const float i_ = sigmoid_f(gi);
            const float f_ = sigmoid_f(gf);
            const float g_ = tanh_f(gc);
            const float o_ = sigmoid_f(go);
            c_reg = f_ * c_reg + i_ * g_;
            const float h_ = o_ * tanh_f(c_reg);
            if (BF16X) {
                out[((size_t)t * NB + gb) * NH + gj] = h_;
                if (t + 1 < NSTEPS) {
                    bf16_t* dst = ((t + 1) & 1) ? hbB : hbA;
                    union { bf16_t b; unsigned short s; } cv; cv.b = (bf16_t)h_;
                    __hip_atomic_store((unsigned short*)&dst[(size_t)gb * NH + gj],
                                       cv.s, __ATOMIC_RELAXED, __HIP_MEMORY_SCOPE_AGENT);
                }
            } else {
                __hip_atomic_store((unsigned*)&out[((size_t)t * NB + gb) * NH + gj],
                                   __float_as_uint(h_),
                                   __ATOMIC_RELAXED, __HIP_MEMORY_SCOPE_AGENT);
            }
        }

        if (t + 1 < NSTEPS) {
            asm volatile("s_waitcnt vmcnt(0)" ::: "memory");  /* h stores at coherence pt */
            BARRIER_LDS();                     /* B6: all waves drained; gbuf reads done */
            if (tid == 0)
                __hip_atomic_store(&gflags[myslot], t + 2,
                                   __ATOMIC_RELAXED, __HIP_MEMORY_SCOPE_AGENT);
            /* x-GEMM(t+1): off the h critical path */
            #pragma unroll
            for (int i = 0; i < 8; ++i) stage4(abuf, tid + i * NTHR, xr[i]);
            BARRIER_LDS();                     /* B7: x staged */
            accx = f32x4_t{ bias_r, bias_r, bias_r, bias_r };
            accx = mfma_phase(0, accx);
        }
    }
}

extern "C" void kernel_launch(void* const* d_in, const int* in_sizes, int n_in,
                              void* d_out, int out_size, void* d_ws, size_t ws_size,
                              hipStream_t stream)
{
    const float* xs  = (const float*)d_in[0];
    const float* h0  = (const float*)d_in[1];
    const float* c0  = (const float*)d_in[2];
    const float* Wih = (const float*)d_in[3];
    const float* Whh = (const float*)d_in[4];
    const float* bih = (const float*)d_in[5];
    const float* bhh = (const float*)d_in[6];
    float* out = (float*)d_out;

    int*    flags = (int*)d_ws;
    bf16_t* hbA   = (bf16_t*)((char*)d_ws + WS_HBUF_OFF);
    bf16_t* hbB   = hbA + (size_t)NB * NH;
    const bool bf16x = (ws_size >= (size_t)WS_NEED_BF16);

    flag_init<<<1, 256, 0, stream>>>(flags);

    void* args[] = { &xs, &h0, &c0, &Wih, &Whh, &bih, &bhh, &out, &hbA, &hbB, &flags };

    if (bf16x) {
        (void)hipFuncSetAttribute(reinterpret_cast<const void*>(lstm_fused<true>),
                                  hipFuncAttributeMaxDynamicSharedMemorySize, SMEM_BYTES);
        hipError_t e = hipLaunchCooperativeKernel((void*)lstm_fused<true>,
                                                  dim3(256), dim3(NTHR), args,
                                                  (unsigned)SMEM_BYTES, stream);
        if (e != hipSuccess) {
            (void)hipGetLastError();
            lstm_fused<true><<<dim3(256), dim3(NTHR), SMEM_BYTES, stream>>>(
                xs, h0, c0, Wih, Whh, bih, bhh, out, hbA, hbB, flags);
        }
    } else {
        (void)hipFuncSetAttribute(reinterpret_cast<const void*>(lstm_fused<false>),
                                  hipFuncAttributeMaxDynamicSharedMemorySize, SMEM_BYTES);
        hipError_t e = hipLaunchCooperativeKernel((void*)lstm_fused<false>,
                                                  dim3(256), dim3(NTHR), args,
                                                  (unsigned)SMEM_BYTES, stream);
        if (e != hipSuccess) {
            (void)hipGetLastError();
            lstm_fused<false><<<dim3(256), dim3(NTHR), SMEM_BYTES, stream>>>(
                xs, h0, c0, Wih, Whh, bih, bhh, out, hbA, hbB, flags);
        }
    }
}